// Round 1
// 10375.372 us; speedup vs baseline: 4.3249x; 4.3249x over previous
//
#include <hip/hip_runtime.h>
#include <hip/hip_bf16.h>

// LSTM: SEQ=2048, BATCH=64, IN=512, HID=512. f32 storage, bf16 MFMA compute.
// Persistent kernel, 4 batch-groups x 64 blocks. Block (g, j) owns batch rows
// [16g,16g+16) and hidden cols [8j,8j+8) (32 gate cols f/i/g/o).
// W slice held in VGPRs as bf16 MFMA B-fragments (converted once).
//
// Sync redesign (this round): NO acquire/release cache maintenance, NO RMW.
//  - h published as packed 2xbf16 u32 via relaxed agent atomic stores
//    (write-through sc1; __syncthreads' vmcnt(0) drain orders them before
//    the flag store).
//  - per-block done flags: writer does ONE relaxed agent store flags[g*64+j]=t+1;
//    readers poll all 64 flags with one lane-parallel relaxed sc1 load and
//    __all(f >= t). No buffer_inv, no buffer_wbl2, no same-address RMW.

#define SEQ 2048
#define NBATCH 64
#define IN_DIM 512
#define HID 512
#define NB 64      // blocks per group
#define GB 16      // batch rows per group

typedef __bf16 bf16x8 __attribute__((ext_vector_type(8)));
typedef short s16x8 __attribute__((ext_vector_type(8)));
typedef float f32x4 __attribute__((ext_vector_type(4)));
typedef unsigned int u32;
typedef unsigned short u16;
typedef u32 u32x4 __attribute__((ext_vector_type(4)));

__global__ void lstm_init(u32* ws) {
    // zero the 256 per-block flags (ws poisoned 0xAA); write-through so the
    // persistent kernel's sc1 reads can't see stale poison.
    __hip_atomic_store(&ws[threadIdx.x], 0u, __ATOMIC_RELAXED,
                       __HIP_MEMORY_SCOPE_AGENT);
}

__device__ inline bf16x8 cvt8(const float* p) {
    f32x4 u = *reinterpret_cast<const f32x4*>(p);
    f32x4 v = *reinterpret_cast<const f32x4*>(p + 4);
    bf16x8 r;
    r[0] = (__bf16)u[0]; r[1] = (__bf16)u[1]; r[2] = (__bf16)u[2]; r[3] = (__bf16)u[3];
    r[4] = (__bf16)v[0]; r[5] = (__bf16)v[1]; r[6] = (__bf16)v[2]; r[7] = (__bf16)v[3];
    return r;
}

__global__ void __launch_bounds__(256, 2) lstm_persistent(
    const float* __restrict__ x,
    const float* __restrict__ Wf, const float* __restrict__ bfp,
    const float* __restrict__ Wi, const float* __restrict__ bip,
    const float* __restrict__ Wg, const float* __restrict__ bgp,
    const float* __restrict__ Wo, const float* __restrict__ bop,
    float* __restrict__ out, u32* __restrict__ flags,
    u32* __restrict__ hbuf /* 2 slots x (64*512/2) u32 of packed bf16 pairs */)
{
    __shared__ short w_lds[256 * 32];        // 16KB W staging (bf16, reused 4x)
    __shared__ float red[4 * 2 * 16 * 16];   // 8KB partial-C reduce buffer

    const int T    = threadIdx.x;
    const int wave = T >> 6;
    const int lane = T & 63;
    const int quad = lane >> 4;
    const int nl   = lane & 15;

    const int g    = blockIdx.x & 3;   // batch group
    const int j    = blockIdx.x >> 2;  // hidden col block
    const int bg0  = g * GB;
    const int hid0 = j * 8;

    const float* Wp[4] = {Wf, Wi, Wg, Wo};

    // ---- one-time: build bf16 B fragments (this wave's K-quarter) ----
    // B-frag layout (16x16x32): lane holds B[k = quad*8 + kk][n = lane&15].
    bf16x8 bfrag[2][8];
    for (int c = 0; c < 4; ++c) {
        for (int it = 0; it < 4; ++it) {
            int i = it * 256 + T;              // [0,1024): (kl, gate)
            int kl = i >> 2, g4 = i & 3;
            int k = c * 256 + kl;
            bf16x8 v = cvt8(Wp[g4] + (size_t)k * HID + hid0);
            *reinterpret_cast<s16x8*>(&w_lds[kl * 32 + g4 * 8]) =
                __builtin_bit_cast(s16x8, v);
        }
        __syncthreads();
        if (wave == c) {
            #pragma unroll
            for (int nt = 0; nt < 2; ++nt)
                #pragma unroll
                for (int ks = 0; ks < 8; ++ks) {
                    s16x8 tmp;
                    int kbase = ks * 32 + quad * 8;
                    int n = nt * 16 + nl;
                    #pragma unroll
                    for (int kk = 0; kk < 8; ++kk)
                        tmp[kk] = w_lds[(kbase + kk) * 32 + n];
                    bfrag[nt][ks] = __builtin_bit_cast(bf16x8, tmp);
                }
        }
        __syncthreads();
    }

    // ---- per-gate-thread persistent state ----
    float bias0 = 0.f, bias1 = 0.f, bias2 = 0.f, bias3 = 0.f, cstate = 0.f;
    if (T < 128) {
        int col = hid0 + (T & 7);
        bias0 = bfp[col]; bias1 = bip[col]; bias2 = bgp[col]; bias3 = bop[col];
    }

    // A-frag element offset: row (bg0+nl), k-within-512 = (wave&1)*256 + quad*8
    const int aoff = (bg0 + nl) * 512 + (wave & 1) * 256 + quad * 8;
    const u32* myFlags = flags + g * NB;   // 64 per-block flags for my group

    for (int t = 0; t < SEQ; ++t) {
        f32x4 acc0 = {0.f, 0.f, 0.f, 0.f};
        f32x4 acc1 = {0.f, 0.f, 0.f, 0.f};

        if (wave < 2) {
            // x-part: no dependency on h — runs ahead, hides barrier wait
            const float* base = x + (size_t)t * (NBATCH * IN_DIM) + aoff;
            #pragma unroll
            for (int ks = 0; ks < 8; ++ks) {
                bf16x8 a = cvt8(base + ks * 32);
                acc0 = __builtin_amdgcn_mfma_f32_16x16x32_bf16(a, bfrag[0][ks], acc0, 0, 0, 0);
                acc1 = __builtin_amdgcn_mfma_f32_16x16x32_bf16(a, bfrag[1][ks], acc1, 0, 0, 0);
            }
        } else if (t > 0) {
            // wait for all 64 blocks of my group to have published h_{t-1}:
            // lane-parallel poll of 64 per-block flags, no invalidate, no RMW.
            const u32 target = (u32)t;
            const u32* fl = myFlags + lane;
            while (true) {
                u32 f = __hip_atomic_load(fl, __ATOMIC_RELAXED,
                                          __HIP_MEMORY_SCOPE_AGENT);
                if (__all((int)(f >= target))) break;
                __builtin_amdgcn_s_sleep(1);
            }
            asm volatile("" ::: "memory");  // no hoisting h loads above poll

            const u32* hb = hbuf
                + (size_t)((t - 1) & 1) * (NBATCH * HID / 2) + (aoff >> 1);
            u32x4 hv[8];
            #pragma unroll
            for (int ks = 0; ks < 8; ++ks) {
                #pragma unroll
                for (int q = 0; q < 4; ++q)
                    hv[ks][q] = __hip_atomic_load(hb + ks * 16 + q,
                                                  __ATOMIC_RELAXED,
                                                  __HIP_MEMORY_SCOPE_AGENT);
            }
            #pragma unroll
            for (int ks = 0; ks < 8; ++ks) {
                bf16x8 a = __builtin_bit_cast(bf16x8, hv[ks]);
                acc0 = __builtin_amdgcn_mfma_f32_16x16x32_bf16(a, bfrag[0][ks], acc0, 0, 0, 0);
                acc1 = __builtin_amdgcn_mfma_f32_16x16x32_bf16(a, bfrag[1][ks], acc1, 0, 0, 0);
            }
        }
        // (waves 2-3 at t==0: h=0, partials stay zero)

        // C/D layout: n = lane&15, m = quad*4 + reg. red[slab][n][m].
        *reinterpret_cast<f32x4*>(&red[((wave * 2 + 0) * 16 + nl) * 16 + quad * 4]) = acc0;
        *reinterpret_cast<f32x4*>(&red[((wave * 2 + 1) * 16 + nl) * 16 + quad * 4]) = acc1;
        __syncthreads();

        if (T < 128) {
            const int m = T >> 3, c8 = T & 7;
            float pre[4];
            #pragma unroll
            for (int q = 0; q < 4; ++q) {
                int n = q * 8 + c8;
                int nt = n >> 4, nn = n & 15;
                float s = 0.f;
                #pragma unroll
                for (int w = 0; w < 4; ++w)
                    s += red[((w * 2 + nt) * 16 + nn) * 16 + m];
                pre[q] = s;
            }
            float fg = 1.f / (1.f + __expf(-(pre[0] + bias0)));
            float ig = 1.f / (1.f + __expf(-(pre[1] + bias1)));
            float gg = 2.f / (1.f + __expf(-2.f * (pre[2] + bias2))) - 1.f;
            float og = 1.f / (1.f + __expf(-(pre[3] + bias3)));
            cstate = fg * cstate + ig * gg;
            float h = og * (2.f / (1.f + __expf(-2.f * cstate)) - 1.f);
            size_t oidx = ((size_t)t * NBATCH + bg0 + m) * HID + hid0 + c8;
            out[oidx] = h;                                      // f32 for checker

            // recurrence publish: pack 2 adjacent cols into one u32,
            // relaxed agent atomic store (write-through, no wbl2 needed).
            u32 mybits = (u32)__builtin_bit_cast(u16, (__bf16)h);
            u32 pbits  = (u32)__shfl_xor((int)mybits, 1, 64);
            if ((T & 1) == 0) {
                u32 packed = mybits | (pbits << 16);
                u32 idx = (u32)((((bg0 + m) * HID) + hid0 + c8) >> 1);
                __hip_atomic_store(hbuf + (size_t)(t & 1) * (NBATCH * HID / 2) + idx,
                                   packed, __ATOMIC_RELAXED,
                                   __HIP_MEMORY_SCOPE_AGENT);
            }
            if (t == SEQ - 1) {
                size_t fin = (size_t)SEQ * NBATCH * HID + (size_t)(bg0 + m) * HID + hid0 + c8;
                out[fin] = h;              // hx
                out[fin + NBATCH * HID] = cstate;  // cx
            }
        }
        // __syncthreads drains vmcnt per-wave: every wave's write-through h
        // stores have retired (IC-visible) before any wave passes the barrier,
        // so the flag store below is safely ordered after them.
        __syncthreads();
        if (T == 0) {
            __hip_atomic_store(const_cast<u32*>(myFlags) + j, (u32)(t + 1),
                               __ATOMIC_RELAXED, __HIP_MEMORY_SCOPE_AGENT);
        }
    }
}

extern "C" void kernel_launch(void* const* d_in, const int* in_sizes, int n_in,
                              void* d_out, int out_size, void* d_ws, size_t ws_size,
                              hipStream_t stream) {
    const float* x  = (const float*)d_in[0];
    const float* Wf = (const float*)d_in[1];
    const float* bf = (const float*)d_in[2];
    const float* Wi = (const float*)d_in[3];
    const float* bi = (const float*)d_in[4];
    const float* Wg = (const float*)d_in[5];
    const float* bg = (const float*)d_in[6];
    const float* Wo = (const float*)d_in[7];
    const float* bo = (const float*)d_in[8];

    u32* flags = (u32*)d_ws;
    u32* hbuf  = (u32*)((char*)d_ws + 4096);

    lstm_init<<<dim3(1), dim3(256), 0, stream>>>(flags);
    lstm_persistent<<<dim3(256), dim3(256), 0, stream>>>(
        x, Wf, bf, Wi, bi, Wg, bg, Wo, bo,
        (float*)d_out, flags, hbuf);
}